// Round 14
// baseline (206.240 us; speedup 1.0000x reference)
//
#include <hip/hip_runtime.h>
#include <stdint.h>

// RNN: B=1024, T=200, D_in=300, D_h=256, D_out=2
// prep:   Wx/Whh pre-scaled by S = 2*log2(e) -> phase2 uses exp2 directly.
// phase1: U' = S*(x @ Wx + bh)^T via swapped mfma (r9 version, no pin).
// phase2: r13 structure (64 blocks, 8 waves x 2 col-tiles, XOR-swizzled h,
//         wave-rotated chunks, own-chunk pre-read, lgkm-only barrier)
//         + T5 s_setprio(1) around the MFMA cluster (waves are phase-skewed
//           at 2/SIMD -> scheduler can favor the MFMA-issuing wave),
//         + U prefetch distance 3 (slots u[0..3], load (s+3)&3),
//         + per-tile tanh->pack->write ordering (tile0 write overlaps
//           tile1 trans).

typedef short s16x8 __attribute__((ext_vector_type(8)));
typedef float f32x4 __attribute__((ext_vector_type(4)));

#define SCL  2.8853900817779268f   // 2*log2(e)

__device__ __forceinline__ unsigned short f2bf(float f){
  uint32_t u = __builtin_bit_cast(uint32_t, f);
  u += 0x7fffu + ((u >> 16) & 1u);           // RNE
  return (unsigned short)(u >> 16);
}
__device__ __forceinline__ uint32_t pack2(float a, float b){
  return (uint32_t)f2bf(a) | ((uint32_t)f2bf(b) << 16);   // a -> low ushort
}
__device__ __forceinline__ float bf2f(unsigned short s){
  uint32_t u = ((uint32_t)s) << 16;
  return __builtin_bit_cast(float, u);
}
// round-half-up bf16 pair pack: 2 adds + 1 v_perm (lo -> low ushort)
__device__ __forceinline__ uint32_t pkrhu(float lo, float hi){
  uint32_t a = __builtin_bit_cast(uint32_t, lo) + 0x8000u;
  uint32_t b = __builtin_bit_cast(uint32_t, hi) + 0x8000u;
  return __builtin_amdgcn_perm(b, a, 0x07060302u);  // bytes: a2,a3,b2,b3
}

// ---------------- prep: weight conversion (pre-scaled by SCL) ----------------
// wxf layout:  [CT=0..15][ki=0..9][lane=0..63][j=0..7]  (K padded 300->320)
// whhf layout: [CT=0..15][ki=0..7][lane=0..63][j=0..7]
// value = S * W[k = ki*32 + (lane>>4)*8 + j][col = CT*16 + (lane&15)]
__global__ void prep_kernel(const float* __restrict__ Wh,
                            unsigned short* __restrict__ wxf,
                            unsigned short* __restrict__ whhf){
  int id = blockIdx.x * 256 + threadIdx.x;
  if (id < 81920){
    int j = id & 7, lane = (id >> 3) & 63, rem = id >> 9;
    int ki = rem % 10, CT = rem / 10;
    int k = ki * 32 + ((lane >> 4) << 3) + j;
    int col = CT * 16 + (lane & 15);
    wxf[id] = (k < 300) ? f2bf(SCL * Wh[k * 256 + col]) : (unsigned short)0;
  } else if (id < 81920 + 65536){
    int id2 = id - 81920;
    int j = id2 & 7, lane = (id2 >> 3) & 63, rem = id2 >> 9;
    int ki = rem & 7, CT = rem >> 3;
    int k = ki * 32 + ((lane >> 4) << 3) + j;
    int col = CT * 16 + (lane & 15);
    whhf[id2] = f2bf(SCL * Wh[(300 + k) * 256 + col]);
  }
}

// ---------------- phase 1: U' = S*(x @ Wx + bh)^T ----------------
// grid: 1600 blocks = 64 batch-tiles x 25 t-groups; 512 threads (8 waves).
__global__ __launch_bounds__(512, 4) void phase1_kernel(
    const float* __restrict__ x, const float* __restrict__ bh,
    const unsigned short* __restrict__ wxf, unsigned short* __restrict__ U){
  __shared__ unsigned short hx[128 * 320];   // 80 KB -> 2 blocks/CU
  int blk = blockIdx.x;
  int bt = blk / 25;
  int t0 = (blk - bt * 25) * 8;
  int tid = threadIdx.x;
  int w = tid >> 6, l = tid & 63;
  int m = l & 15, kg = l >> 4;

  const float4* xb = (const float4*)x + (long)(bt * 16) * 15000 + t0 * 75;
  for (int i = tid; i < 9600; i += 512){
    int bl = i / 600;
    int j  = i - bl * 600;
    float4 v = xb[(long)bl * 15000 + j];
    int tt = j / 75;
    int k4 = j - tt * 75;
    int idx = (((tt * 16 + bl) * 320) + k4 * 4) ^ ((bl & 7) << 3);
    *(uint2*)(&hx[idx]) = make_uint2(pack2(v.x, v.y), pack2(v.z, v.w));
  }
  for (int i = tid; i < 640; i += 512){
    int r = i / 5, q = i - r * 5;
    int idx = (r * 320 + 300 + q * 4) ^ ((r & 7) << 3);
    *(uint2*)(&hx[idx]) = make_uint2(0u, 0u);
  }

  s16x8 Bf0[10], Bf1[10];
  const unsigned short* w0p = wxf + (2 * w + 0) * 5120 + l * 8;
  const unsigned short* w1p = wxf + (2 * w + 1) * 5120 + l * 8;
#pragma unroll
  for (int ki = 0; ki < 10; ki++){
    Bf0[ki] = *(const s16x8*)(w0p + ki * 512);
    Bf1[ki] = *(const s16x8*)(w1p + ki * 512);
  }
  float4 bv0 = *(const float4*)(bh + (2 * w + 0) * 16 + kg * 4);
  float4 bv1 = *(const float4*)(bh + (2 * w + 1) * 16 + kg * 4);
  bv0.x *= SCL; bv0.y *= SCL; bv0.z *= SCL; bv0.w *= SCL;
  bv1.x *= SCL; bv1.y *= SCL; bv1.z *= SCL; bv1.w *= SCL;
  __syncthreads();

  int abase = m * 320 + kg * 8;
  int swz = (m & 7) << 3;
#pragma unroll 1
  for (int tt = 0; tt < 8; tt++){
    f32x4 acc0 = {bv0.x, bv0.y, bv0.z, bv0.w};
    f32x4 acc1 = {bv1.x, bv1.y, bv1.z, bv1.w};
    int ab = tt * 5120 + abase;
#pragma unroll
    for (int ki = 0; ki < 10; ki++){
      s16x8 a = *(const s16x8*)(&hx[(ab + ki * 32) ^ swz]);
      acc0 = __builtin_amdgcn_mfma_f32_16x16x32_bf16(Bf0[ki], a, acc0, 0, 0, 0);
      acc1 = __builtin_amdgcn_mfma_f32_16x16x32_bf16(Bf1[ki], a, acc1, 0, 0, 0);
    }
    long base = (long)(bt * 200 + t0 + tt) * 4096;
    uint4 s;
    s.x = pack2(acc0[0], acc0[1]);
    s.y = pack2(acc0[2], acc0[3]);
    s.z = pack2(acc1[0], acc1[1]);
    s.w = pack2(acc1[2], acc1[3]);
    *(uint4*)(U + base + w * 512 + l * 8) = s;   // wave: 1KB contiguous
  }
}

// ---------------- phase 2: serial recurrence ----------------
// grid: 64 blocks (16 batch rows), 512 threads (8 waves x 2 col-tiles).
__global__ __launch_bounds__(512, 2) void phase2_kernel(
    const unsigned short* __restrict__ U, const unsigned short* __restrict__ whhf,
    const float* __restrict__ Wo, const float* __restrict__ bo,
    float* __restrict__ out){
  __shared__ unsigned short h2[2][16 * 272];  // stride 272, XOR-swizzled rows
  __shared__ float flds[16][272];
  int bt = blockIdx.x;
  int tid = threadIdx.x;
  int w = tid >> 6, l = tid & 63;
  int n = l & 15, kg = l >> 4;
  int sw = ((n >> 2) & 1) << 3;               // ushort-bit-3 row swizzle

  // Whh A-fragments in WAVE-ROTATED order: slot j holds chunk ki=(j+w)&7
  s16x8 Bf0[8], Bf1[8];
  int roff[8];
#pragma unroll
  for (int j = 0; j < 8; j++){
    int ki = (j + w) & 7;
    roff[j] = ki * 32;
    Bf0[j] = *(const s16x8*)(whhf + ((2 * w + 0) * 8 + ki) * 512 + l * 8);
    Bf1[j] = *(const s16x8*)(whhf + ((2 * w + 1) * 8 + ki) * 512 + l * 8);
  }

  for (int i = tid; i < 16 * 272; i += 512) h2[0][i] = 0;  // h0 = 0

  const unsigned short* ub = U + (long)bt * 819200 + w * 512 + l * 8;
  s16x8 u[4];
  u[0] = *(const s16x8*)(ub);                // t = 0
  u[1] = *(const s16x8*)(ub + 4096);         // t = 1
  u[2] = *(const s16x8*)(ub + 2 * 4096);     // t = 2
  __syncthreads();

  int rbase = (n * 272 + kg * 8) ^ sw;         // + ki*32 never carries into bit 3
  int wbase = (n * 272 + kg * 4) ^ sw;         // + (2w+c)*16 never touches bit 3

  s16x8 a_pre;                                 // own chunk (ki = w) of h(t-1)
#pragma unroll
  for (int j = 0; j < 8; j++) a_pre[j] = 0;    // h0 = 0

  float hv[8];
  for (int tq = 0; tq < 50; ++tq){
    // pin weight frags: only legal source of the value = the register
#pragma unroll
    for (int j = 0; j < 8; j++){
      asm volatile("" : "+v"(Bf0[j]), "+v"(Bf1[j]));
    }
#pragma unroll
    for (int s = 0; s < 4; ++s){
      int t = tq * 4 + s;
      int tf = t + 3; if (tf > 199) tf = 199;
      u[(s + 3) & 3] = *(const s16x8*)(ub + (long)tf * 4096);  // static slot, dist 3

      s16x8 a[8];
      a[0] = a_pre;                            // own chunk, pre-read last step
#pragma unroll
      for (int j = 1; j < 8; j++)
        a[j] = *(const s16x8*)(&h2[s & 1][rbase + roff[j]]);

      f32x4 acc0, acc1;
#pragma unroll
      for (int r = 0; r < 4; r++){
        acc0[r] = bf2f((unsigned short)u[s][r]);        // s: compile-time
        acc1[r] = bf2f((unsigned short)u[s][4 + r]);
      }
      // MFMA cluster: boost this wave's priority while it feeds the matrix pipe
      __builtin_amdgcn_s_setprio(1);
#pragma unroll
      for (int j = 0; j < 8; j++){
        acc0 = __builtin_amdgcn_mfma_f32_16x16x32_bf16(Bf0[j], a[j], acc0, 0, 0, 0);
        acc1 = __builtin_amdgcn_mfma_f32_16x16x32_bf16(Bf1[j], a[j], acc1, 0, 0, 0);
      }
      __builtin_amdgcn_s_setprio(0);
      // tile 0: tanh -> pack -> write (write overlaps tile 1 trans)
#pragma unroll
      for (int i = 0; i < 4; i++){
        float e = __builtin_amdgcn_exp2f(acc0[i]);
        hv[i] = fmaf(-2.f, __builtin_amdgcn_rcpf(e + 1.f), 1.f);
      }
      *(uint2*)(&h2[(s & 1) ^ 1][wbase + (2 * w + 0) * 16]) =
          make_uint2(pkrhu(hv[0], hv[1]), pkrhu(hv[2], hv[3]));
      // tile 1
#pragma unroll
      for (int i = 0; i < 4; i++){
        float e = __builtin_amdgcn_exp2f(acc1[i]);
        hv[4 + i] = fmaf(-2.f, __builtin_amdgcn_rcpf(e + 1.f), 1.f);
      }
      *(uint2*)(&h2[(s & 1) ^ 1][wbase + (2 * w + 1) * 16]) =
          make_uint2(pkrhu(hv[4], hv[5]), pkrhu(hv[6], hv[7]));
      // pre-read own chunk of h(t) from the just-written buffer (same-wave
      // DS ordering guarantees freshness; other waves' chunks need barrier)
      a_pre = *(const s16x8*)(&h2[(s & 1) ^ 1][rbase + roff[0]]);
      // barrier WITHOUT vmcnt drain: LDS ordering only (T4) -- U prefetch
      // loads stay in flight across the barrier.
      asm volatile("s_waitcnt lgkmcnt(0)\n\ts_barrier" ::: "memory");
    }
  }

  // -------- output head: pre_out = clip(h @ Wo + bo), log_softmax --------
#pragma unroll
  for (int i = 0; i < 8; i++){
    int r = i & 3, c = i >> 2;
    flds[n][(2 * w + c) * 16 + kg * 4 + r] = hv[i];
  }
  __syncthreads();
  int row = tid >> 5, q = tid & 31;
  float p0 = 0.f, p1 = 0.f;
#pragma unroll
  for (int jj = 0; jj < 8; jj++){
    float hvv = flds[row][q + 32 * jj];
    p0 += hvv * Wo[(q + 32 * jj) * 2 + 0];
    p1 += hvv * Wo[(q + 32 * jj) * 2 + 1];
  }
#pragma unroll
  for (int mm = 16; mm >= 1; mm >>= 1){
    p0 += __shfl_xor(p0, mm, 32);
    p1 += __shfl_xor(p1, mm, 32);
  }
  if (q == 0){
    p0 = fminf(fmaxf(p0 + bo[0], -4.f), 4.f);
    p1 = fminf(fmaxf(p1 + bo[1], -4.f), 4.f);
    float mx = fmaxf(p0, p1);
    float lse = mx + logf(__expf(p0 - mx) + __expf(p1 - mx));
    int orow = bt * 16 + row;
    out[orow * 2 + 0] = p0 - lse;
    out[orow * 2 + 1] = p1 - lse;
  }
}

extern "C" void kernel_launch(void* const* d_in, const int* in_sizes, int n_in,
                              void* d_out, int out_size, void* d_ws, size_t ws_size,
                              hipStream_t stream){
  const float* x  = (const float*)d_in[0];
  const float* Wh = (const float*)d_in[1];
  const float* bh = (const float*)d_in[2];
  const float* Wo = (const float*)d_in[3];
  const float* bo = (const float*)d_in[4];
  float* out = (float*)d_out;

  unsigned short* U    = (unsigned short*)d_ws;                               // 104857600 B
  unsigned short* wxf  = (unsigned short*)((char*)d_ws + 104857600);          // 163840 B
  unsigned short* whhf = (unsigned short*)((char*)d_ws + 104857600 + 163840); // 131072 B

  prep_kernel<<<576, 256, 0, stream>>>(Wh, wxf, whhf);
  phase1_kernel<<<1600, 512, 0, stream>>>(x, bh, wxf, U);
  phase2_kernel<<<64, 512, 0, stream>>>(U, whhf, Wo, bo, out);
}

// Round 15
// 204.084 us; speedup vs baseline: 1.0106x; 1.0106x over previous
//
#include <hip/hip_runtime.h>
#include <stdint.h>

// RNN: B=1024, T=200, D_in=300, D_h=256, D_out=2   [FINAL — r13 config]
// prep:   Wx/Whh pre-scaled by S = 2*log2(e) -> phase2 uses exp2 directly.
// phase1: U' = S*(x @ Wx + bh)^T via swapped mfma(Wfrag, xfrag); lane stores
//         one uint4 at w*512+l*8 (wave writes 1KB contiguous), read back
//         verbatim by phase2 as its accumulator init.
// phase2: 64 blocks x 16 batch rows, 8 waves x 2 col-tiles (2 waves/SIMD):
//         - Whh frags resident via in-loop asm pin (r5/r6: without it the
//           compiler reloads 64 regs from L2 every step),
//         - XOR-swizzled h LDS (bit-3 of ushort idx): bank-conflict-free
//           reads AND writes (r9: conflicts 2.48M -> 0.84M),
//         - wave-rotated K-chunks + own-chunk pre-read (first MFMA operand
//           needs no post-barrier LDS read),
//         - static u[4] rotation prefetch, distance 2 (r6: vmcnt wait lands
//           2 steps after issue),
//         - lgkm-only barrier (T4: U loads stay in flight across barrier),
//         - exp2-tanh without clamp (bf16-invisible beyond |4|), pkrhu pack.
// Plateau note: phase2 ~140us is latency/phase-serialization bound at
// MfmaUtil ~7%; structural alternatives (1 wave/SIMD, 4-wave, dual-half
// soft-sync, producer/consumer fusion x2, setprio, deeper prefetch) all
// measured neutral-to-worse (r7,r8,r11,r12,r14).

typedef short s16x8 __attribute__((ext_vector_type(8)));
typedef float f32x4 __attribute__((ext_vector_type(4)));

#define SCL  2.8853900817779268f   // 2*log2(e)

__device__ __forceinline__ unsigned short f2bf(float f){
  uint32_t u = __builtin_bit_cast(uint32_t, f);
  u += 0x7fffu + ((u >> 16) & 1u);           // RNE
  return (unsigned short)(u >> 16);
}
__device__ __forceinline__ uint32_t pack2(float a, float b){
  return (uint32_t)f2bf(a) | ((uint32_t)f2bf(b) << 16);   // a -> low ushort
}
__device__ __forceinline__ float bf2f(unsigned short s){
  uint32_t u = ((uint32_t)s) << 16;
  return __builtin_bit_cast(float, u);
}
// round-half-up bf16 pair pack: 2 adds + 1 v_perm (lo -> low ushort)
__device__ __forceinline__ uint32_t pkrhu(float lo, float hi){
  uint32_t a = __builtin_bit_cast(uint32_t, lo) + 0x8000u;
  uint32_t b = __builtin_bit_cast(uint32_t, hi) + 0x8000u;
  return __builtin_amdgcn_perm(b, a, 0x07060302u);  // bytes: a2,a3,b2,b3
}

// ---------------- prep: weight conversion (pre-scaled by SCL) ----------------
// wxf layout:  [CT=0..15][ki=0..9][lane=0..63][j=0..7]  (K padded 300->320)
// whhf layout: [CT=0..15][ki=0..7][lane=0..63][j=0..7]
// value = S * W[k = ki*32 + (lane>>4)*8 + j][col = CT*16 + (lane&15)]
__global__ void prep_kernel(const float* __restrict__ Wh,
                            unsigned short* __restrict__ wxf,
                            unsigned short* __restrict__ whhf){
  int id = blockIdx.x * 256 + threadIdx.x;
  if (id < 81920){
    int j = id & 7, lane = (id >> 3) & 63, rem = id >> 9;
    int ki = rem % 10, CT = rem / 10;
    int k = ki * 32 + ((lane >> 4) << 3) + j;
    int col = CT * 16 + (lane & 15);
    wxf[id] = (k < 300) ? f2bf(SCL * Wh[k * 256 + col]) : (unsigned short)0;
  } else if (id < 81920 + 65536){
    int id2 = id - 81920;
    int j = id2 & 7, lane = (id2 >> 3) & 63, rem = id2 >> 9;
    int ki = rem & 7, CT = rem >> 3;
    int k = ki * 32 + ((lane >> 4) << 3) + j;
    int col = CT * 16 + (lane & 15);
    whhf[id2] = f2bf(SCL * Wh[(300 + k) * 256 + col]);
  }
}

// ---------------- phase 1: U' = S*(x @ Wx + bh)^T ----------------
// grid: 1600 blocks = 64 batch-tiles x 25 t-groups; 512 threads (8 waves).
__global__ __launch_bounds__(512, 4) void phase1_kernel(
    const float* __restrict__ x, const float* __restrict__ bh,
    const unsigned short* __restrict__ wxf, unsigned short* __restrict__ U){
  __shared__ unsigned short hx[128 * 320];   // 80 KB -> 2 blocks/CU
  int blk = blockIdx.x;
  int bt = blk / 25;
  int t0 = (blk - bt * 25) * 8;
  int tid = threadIdx.x;
  int w = tid >> 6, l = tid & 63;
  int m = l & 15, kg = l >> 4;

  const float4* xb = (const float4*)x + (long)(bt * 16) * 15000 + t0 * 75;
  for (int i = tid; i < 9600; i += 512){
    int bl = i / 600;
    int j  = i - bl * 600;
    float4 v = xb[(long)bl * 15000 + j];
    int tt = j / 75;
    int k4 = j - tt * 75;
    int idx = (((tt * 16 + bl) * 320) + k4 * 4) ^ ((bl & 7) << 3);
    *(uint2*)(&hx[idx]) = make_uint2(pack2(v.x, v.y), pack2(v.z, v.w));
  }
  for (int i = tid; i < 640; i += 512){
    int r = i / 5, q = i - r * 5;
    int idx = (r * 320 + 300 + q * 4) ^ ((r & 7) << 3);
    *(uint2*)(&hx[idx]) = make_uint2(0u, 0u);
  }

  s16x8 Bf0[10], Bf1[10];
  const unsigned short* w0p = wxf + (2 * w + 0) * 5120 + l * 8;
  const unsigned short* w1p = wxf + (2 * w + 1) * 5120 + l * 8;
#pragma unroll
  for (int ki = 0; ki < 10; ki++){
    Bf0[ki] = *(const s16x8*)(w0p + ki * 512);
    Bf1[ki] = *(const s16x8*)(w1p + ki * 512);
  }
  float4 bv0 = *(const float4*)(bh + (2 * w + 0) * 16 + kg * 4);
  float4 bv1 = *(const float4*)(bh + (2 * w + 1) * 16 + kg * 4);
  bv0.x *= SCL; bv0.y *= SCL; bv0.z *= SCL; bv0.w *= SCL;
  bv1.x *= SCL; bv1.y *= SCL; bv1.z *= SCL; bv1.w *= SCL;
  __syncthreads();

  int abase = m * 320 + kg * 8;
  int swz = (m & 7) << 3;
#pragma unroll 1
  for (int tt = 0; tt < 8; tt++){
    f32x4 acc0 = {bv0.x, bv0.y, bv0.z, bv0.w};
    f32x4 acc1 = {bv1.x, bv1.y, bv1.z, bv1.w};
    int ab = tt * 5120 + abase;
#pragma unroll
    for (int ki = 0; ki < 10; ki++){
      s16x8 a = *(const s16x8*)(&hx[(ab + ki * 32) ^ swz]);
      acc0 = __builtin_amdgcn_mfma_f32_16x16x32_bf16(Bf0[ki], a, acc0, 0, 0, 0);
      acc1 = __builtin_amdgcn_mfma_f32_16x16x32_bf16(Bf1[ki], a, acc1, 0, 0, 0);
    }
    long base = (long)(bt * 200 + t0 + tt) * 4096;
    uint4 s;
    s.x = pack2(acc0[0], acc0[1]);
    s.y = pack2(acc0[2], acc0[3]);
    s.z = pack2(acc1[0], acc1[1]);
    s.w = pack2(acc1[2], acc1[3]);
    *(uint4*)(U + base + w * 512 + l * 8) = s;   // wave: 1KB contiguous
  }
}

// ---------------- phase 2: serial recurrence ----------------
// grid: 64 blocks (16 batch rows), 512 threads (8 waves x 2 col-tiles).
__global__ __launch_bounds__(512, 2) void phase2_kernel(
    const unsigned short* __restrict__ U, const unsigned short* __restrict__ whhf,
    const float* __restrict__ Wo, const float* __restrict__ bo,
    float* __restrict__ out){
  __shared__ unsigned short h2[2][16 * 272];  // stride 272, XOR-swizzled rows
  __shared__ float flds[16][272];
  int bt = blockIdx.x;
  int tid = threadIdx.x;
  int w = tid >> 6, l = tid & 63;
  int n = l & 15, kg = l >> 4;
  int sw = ((n >> 2) & 1) << 3;               // ushort-bit-3 row swizzle

  // Whh A-fragments in WAVE-ROTATED order: slot j holds chunk ki=(j+w)&7
  s16x8 Bf0[8], Bf1[8];
  int roff[8];
#pragma unroll
  for (int j = 0; j < 8; j++){
    int ki = (j + w) & 7;
    roff[j] = ki * 32;
    Bf0[j] = *(const s16x8*)(whhf + ((2 * w + 0) * 8 + ki) * 512 + l * 8);
    Bf1[j] = *(const s16x8*)(whhf + ((2 * w + 1) * 8 + ki) * 512 + l * 8);
  }

  for (int i = tid; i < 16 * 272; i += 512) h2[0][i] = 0;  // h0 = 0

  const unsigned short* ub = U + (long)bt * 819200 + w * 512 + l * 8;
  s16x8 u[4];
  u[0] = *(const s16x8*)(ub);            // t = 0
  u[1] = *(const s16x8*)(ub + 4096);     // t = 1
  __syncthreads();

  int rbase = (n * 272 + kg * 8) ^ sw;         // + ki*32 never carries into bit 3
  int wbase = (n * 272 + kg * 4) ^ sw;         // + (2w+c)*16 never touches bit 3

  s16x8 a_pre;                                 // own chunk (ki = w) of h(t-1)
#pragma unroll
  for (int j = 0; j < 8; j++) a_pre[j] = 0;    // h0 = 0

  float hv[8];
  for (int tq = 0; tq < 50; ++tq){
    // pin weight frags: only legal source of the value = the register
#pragma unroll
    for (int j = 0; j < 8; j++){
      asm volatile("" : "+v"(Bf0[j]), "+v"(Bf1[j]));
    }
#pragma unroll
    for (int s = 0; s < 4; ++s){
      int t = tq * 4 + s;
      int tf = (t < 198) ? t + 2 : 199;
      u[(s + 2) & 3] = *(const s16x8*)(ub + (long)tf * 4096);  // static slot

      s16x8 a[8];
      a[0] = a_pre;                            // own chunk, pre-read last step
#pragma unroll
      for (int j = 1; j < 8; j++)
        a[j] = *(const s16x8*)(&h2[s & 1][rbase + roff[j]]);

      f32x4 acc0, acc1;
#pragma unroll
      for (int r = 0; r < 4; r++){
        acc0[r] = bf2f((unsigned short)u[s][r]);        // s: compile-time
        acc1[r] = bf2f((unsigned short)u[s][4 + r]);
      }
      // 2 independent chains of depth 8; j=0 operand already in registers
#pragma unroll
      for (int j = 0; j < 8; j++){
        acc0 = __builtin_amdgcn_mfma_f32_16x16x32_bf16(Bf0[j], a[j], acc0, 0, 0, 0);
        acc1 = __builtin_amdgcn_mfma_f32_16x16x32_bf16(Bf1[j], a[j], acc1, 0, 0, 0);
      }
      // tanh(pre) = 1 - 2/(exp2(S*pre)+1); no clamp needed (bf16-invisible)
#pragma unroll
      for (int i = 0; i < 8; i++){
        float v = (i < 4) ? acc0[i] : acc1[i - 4];
        float e = __builtin_amdgcn_exp2f(v);
        hv[i] = fmaf(-2.f, __builtin_amdgcn_rcpf(e + 1.f), 1.f);
      }
      // packed h writes: tile T=2w+c, col T*16+kg*4+r
      {
        uint2 d0 = make_uint2(pkrhu(hv[0], hv[1]), pkrhu(hv[2], hv[3]));
        uint2 d1 = make_uint2(pkrhu(hv[4], hv[5]), pkrhu(hv[6], hv[7]));
        *(uint2*)(&h2[(s & 1) ^ 1][wbase + (2 * w + 0) * 16]) = d0;
        *(uint2*)(&h2[(s & 1) ^ 1][wbase + (2 * w + 1) * 16]) = d1;
      }
      // pre-read own chunk of h(t) from the just-written buffer (same-wave
      // DS ordering guarantees freshness; other waves' chunks need barrier)
      a_pre = *(const s16x8*)(&h2[(s & 1) ^ 1][rbase + roff[0]]);
      // barrier WITHOUT vmcnt drain: LDS ordering only (T4) -- U prefetch
      // loads stay in flight across the barrier.
      asm volatile("s_waitcnt lgkmcnt(0)\n\ts_barrier" ::: "memory");
    }
  }

  // -------- output head: pre_out = clip(h @ Wo + bo), log_softmax --------
#pragma unroll
  for (int i = 0; i < 8; i++){
    int r = i & 3, c = i >> 2;
    flds[n][(2 * w + c) * 16 + kg * 4 + r] = hv[i];
  }
  __syncthreads();
  int row = tid >> 5, q = tid & 31;
  float p0 = 0.f, p1 = 0.f;
#pragma unroll
  for (int jj = 0; jj < 8; jj++){
    float hvv = flds[row][q + 32 * jj];
    p0 += hvv * Wo[(q + 32 * jj) * 2 + 0];
    p1 += hvv * Wo[(q + 32 * jj) * 2 + 1];
  }
#pragma unroll
  for (int mm = 16; mm >= 1; mm >>= 1){
    p0 += __shfl_xor(p0, mm, 32);
    p1 += __shfl_xor(p1, mm, 32);
  }
  if (q == 0){
    p0 = fminf(fmaxf(p0 + bo[0], -4.f), 4.f);
    p1 = fminf(fmaxf(p1 + bo[1], -4.f), 4.f);
    float mx = fmaxf(p0, p1);
    float lse = mx + logf(__expf(p0 - mx) + __expf(p1 - mx));
    int orow = bt * 16 + row;
    out[orow * 2 + 0] = p0 - lse;
    out[orow * 2 + 1] = p1 - lse;
  }
}

extern "C" void kernel_launch(void* const* d_in, const int* in_sizes, int n_in,
                              void* d_out, int out_size, void* d_ws, size_t ws_size,
                              hipStream_t stream){
  const float* x  = (const float*)d_in[0];
  const float* Wh = (const float*)d_in[1];
  const float* bh = (const float*)d_in[2];
  const float* Wo = (const float*)d_in[3];
  const float* bo = (const float*)d_in[4];
  float* out = (float*)d_out;

  unsigned short* U    = (unsigned short*)d_ws;                               // 104857600 B
  unsigned short* wxf  = (unsigned short*)((char*)d_ws + 104857600);          // 163840 B
  unsigned short* whhf = (unsigned short*)((char*)d_ws + 104857600 + 163840); // 131072 B

  prep_kernel<<<576, 256, 0, stream>>>(Wh, wxf, whhf);
  phase1_kernel<<<1600, 512, 0, stream>>>(x, bh, wxf, U);
  phase2_kernel<<<64, 512, 0, stream>>>(U, whhf, Wo, bo, out);
}